// Round 21
// baseline (126.135 us; speedup 1.0000x reference)
//
#include <hip/hip_runtime.h>
#include <hip/hip_bf16.h>

#define N_NODES 50000
#define NIN 512
#define NH 96
#define NL 32
#define NH2 64

#define NB2 196          // coarse buckets of 256 nodes
#define NBLK 128         // binning blocks
#define BCAP 5120        // fixed region capacity per bucket (E[cnt]=4096, +16 sigma)
#define ECH 6250         // edges per coarse block (800000/128)

typedef __attribute__((ext_vector_type(8))) short short8v;   // 8 bf16 (4 VGPR)
typedef __attribute__((ext_vector_type(4))) float f32x4;

__device__ __forceinline__ unsigned short f2bf(float f) {    // RNE via native cvt
    __hip_bfloat16 h = __float2bfloat16(f);
    unsigned short u;
    __builtin_memcpy(&u, &h, 2);
    return u;
}
__device__ __forceinline__ float bflo(unsigned u) { return __uint_as_float(u << 16); }
__device__ __forceinline__ float bfhi(unsigned u) { return __uint_as_float(u & 0xFFFF0000u); }

// fused: WbT = W1^T bf16; W2T = [Wmu|Wls]^T bf16; gcur = 0
__global__ __launch_bounds__(256) void k_prep(const float* __restrict__ W1,
                                              const float* __restrict__ Wmu,
                                              const float* __restrict__ Wls,
                                              unsigned short* __restrict__ WbT,
                                              unsigned short* __restrict__ W2T,
                                              int* __restrict__ gcur) {
    int idx = blockIdx.x * 256 + threadIdx.x;
    if (idx < NH * NIN) {
        int n = idx >> 9, k = idx & 511;
        WbT[idx] = f2bf(W1[(size_t)k * NH + n]);
    } else if (idx < NH * NIN + NH2 * NH) {
        int j = idx - NH * NIN;
        int n = j / NH, k = j - n * NH;
        float v = (n < NL) ? Wmu[k * NL + n] : Wls[k * NL + (n - NL)];
        W2T[j] = f2bf(v);
    }
    if (idx < NB2) gcur[idx] = 0;
}

// pass A: privatized block-run binning; packed pairs cached in LDS during the
// histogram pass. Runs contiguous -> each cache line owned by one block/XCD.
__global__ __launch_bounds__(256) void k_coarse(const int* __restrict__ src,
                                                const int* __restrict__ dst,
                                                int* __restrict__ gcur,
                                                unsigned* __restrict__ cpair, int E) {
    __shared__ unsigned epk[ECH];
    __shared__ int hist[NB2];
    __shared__ int lpos[NB2];
    int t = threadIdx.x;
    int ch = (E + NBLK - 1) / NBLK;
    int e0 = blockIdx.x * ch, e1 = min(e0 + ch, E);
    int n = e1 - e0;
    for (int b = t; b < NB2; b += 256) hist[b] = 0;
    __syncthreads();
    for (int li = t; li < n; li += 256) {
        int s = src[e0 + li], d = dst[e0 + li];
        epk[li] = (unsigned)s | ((unsigned)d << 16);
        atomicAdd(&hist[d >> 8], 1);
    }
    __syncthreads();
    for (int b = t; b < NB2; b += 256) {
        int cnt = hist[b];
        int base = (cnt > 0) ? atomicAdd(&gcur[b], cnt) : 0;
        lpos[b] = b * BCAP + base;
    }
    __syncthreads();
    for (int li = t; li < n; li += 256) {
        unsigned u = epk[li];
        int pos = atomicAdd(&lpos[u >> 24], 1);
        cpair[pos] = u;
    }
}

// pass B: one block per bucket. Computes its own global base, derives per-node
// counts + rowoff + dis, places edges into the bucket's private esrc window.
__global__ __launch_bounds__(256) void k_fine(const unsigned* __restrict__ cpair,
                                              const int* __restrict__ gcur,
                                              int* __restrict__ rowoff,
                                              float* __restrict__ dis,
                                              int* __restrict__ esrc) {
    __shared__ int lcnt[256];
    __shared__ int lscan[256];
    int bb = blockIdx.x;
    int n0 = bb << 8;
    int t = threadIdx.x;
    lscan[t] = (t < bb) ? gcur[t] : 0;
    __syncthreads();
    for (int off = 128; off > 0; off >>= 1) {
        if (t < off) lscan[t] += lscan[t + off];
        __syncthreads();
    }
    int base = lscan[0];
    if (bb == NB2 - 1 && t == 0) rowoff[N_NODES] = base + gcur[bb];
    lcnt[t] = 0;
    __syncthreads();
    int p0 = bb * BCAP;
    int p1 = p0 + gcur[bb];
    for (int p = p0 + t; p < p1; p += 256)
        atomicAdd(&lcnt[(cpair[p] >> 16) - n0], 1);
    __syncthreads();
    int cnt = lcnt[t];
    lscan[t] = cnt;
    __syncthreads();
    for (int off = 1; off < 256; off <<= 1) {
        int u = (t >= off) ? lscan[t - off] : 0;
        __syncthreads();
        lscan[t] += u;
        __syncthreads();
    }
    int excl = lscan[t] - cnt;
    int node = n0 + t;
    if (node < N_NODES) {
        rowoff[node] = base + excl;
        dis[node] = rsqrtf((float)cnt + 1.0f);
    }
    lcnt[t] = base + excl;
    __syncthreads();
    for (int p = p0 + t; p < p1; p += 256) {
        unsigned u = cpair[p];
        int d = (int)(u >> 16);
        int pos = atomicAdd(&lcnt[d - n0], 1);
        esrc[pos] = (int)(u & 0xFFFFu);
    }
}

// h' = (x @ W1) * dis[row], bf16 MFMA 16x16x32 (r20 measured-best config).
// BM=64 (4 waves x 16 rows), BK=128 -> 4 K-tiles, 3 blocks/CU (40KB LDS).
// LDS rows 256B = 16 slots; slot ^= (row&7): conflict-free frag reads.
#define GBM 64
__global__ __launch_bounds__(256, 3) void k_gemm1(const float* __restrict__ x,
                                                  const unsigned short* __restrict__ WbT,
                                                  const float* __restrict__ dis,
                                                  unsigned short* __restrict__ hb, int M) {
    __shared__ __align__(16) char lA[64 * 256];    // 16 KB
    __shared__ __align__(16) char lB[96 * 256];    // 24 KB
    int tid = threadIdx.x;
    int lane = tid & 63, w = tid >> 6;
    int l15 = lane & 15, hi = lane >> 4;
    int m0 = blockIdx.x * GBM;

    f32x4 acc[6];
#pragma unroll
    for (int nt = 0; nt < 6; ++nt)
#pragma unroll
        for (int i = 0; i < 4; ++i) acc[nt][i] = 0.f;

    int key = l15 & 7;
    int arow = (w * 16 + l15) * 256;

    for (int kt = 0; kt < 4; ++kt) {
        __syncthreads();
#pragma unroll
        for (int i = 0; i < 4; ++i) {
            int s = i * 256 + tid;
            int r = s >> 4, sl = s & 15;
            const float* p = x + (size_t)min(m0 + r, M - 1) * NIN + kt * 128 + sl * 8;
            float4 a0 = *reinterpret_cast<const float4*>(p);
            float4 a1 = *reinterpret_cast<const float4*>(p + 4);
            uint4 pk;
            pk.x = (unsigned)f2bf(a0.x) | ((unsigned)f2bf(a0.y) << 16);
            pk.y = (unsigned)f2bf(a0.z) | ((unsigned)f2bf(a0.w) << 16);
            pk.z = (unsigned)f2bf(a1.x) | ((unsigned)f2bf(a1.y) << 16);
            pk.w = (unsigned)f2bf(a1.z) | ((unsigned)f2bf(a1.w) << 16);
            *reinterpret_cast<uint4*>(lA + r * 256 + ((sl ^ (r & 7)) << 4)) = pk;
        }
#pragma unroll
        for (int i = 0; i < 6; ++i) {
            int s = i * 256 + tid;
            int n = s >> 4, sl = s & 15;
            uint4 bv = *reinterpret_cast<const uint4*>(WbT + (size_t)n * NIN + kt * 128 + sl * 8);
            *reinterpret_cast<uint4*>(lB + n * 256 + ((sl ^ (n & 7)) << 4)) = bv;
        }
        __syncthreads();

#pragma unroll
        for (int kc = 0; kc < 4; ++kc) {
            int off = (((kc * 4 + hi) ^ key) << 4);
            short8v a = *reinterpret_cast<const short8v*>(lA + arow + off);
#pragma unroll
            for (int nt = 0; nt < 6; ++nt) {
                short8v bv = *reinterpret_cast<const short8v*>(lB + (nt * 16 + l15) * 256 + off);
                acc[nt] = __builtin_amdgcn_mfma_f32_16x16x32_bf16(a, bv, acc[nt], 0, 0, 0);
            }
        }
    }

    int rbase = m0 + w * 16 + hi * 4;
#pragma unroll
    for (int r = 0; r < 4; ++r) {
        int orow = rbase + r;
        if (orow < M) {
            float dv = dis[orow];
            unsigned short* op = hb + (size_t)orow * NH + l15;
#pragma unroll
            for (int nt = 0; nt < 6; ++nt) op[nt * 16] = f2bf(acc[nt][r] * dv);
        }
    }
}

// gather layer 1: hid = relu((sum h'[s] + h'[i]) * dis + b1).
// 16-lane groups x TWO nodes each (interleaved accumulators) -> 8 independent
// row-streams per wave. Negative-nb predication handles unequal degrees.
__global__ __launch_bounds__(256) void k_gather1(const uint4* __restrict__ hb4,
                                                 const int* __restrict__ rowoff,
                                                 const int* __restrict__ esrc,
                                                 const float* __restrict__ dis,
                                                 const float* __restrict__ b1,
                                                 uint4* __restrict__ hid4) {
    int tid = threadIdx.x;
    int g = tid >> 4, c = tid & 15;
    int nodeA = blockIdx.x * 32 + g * 2;
    if (nodeA >= N_NODES) return;
    int nodeB = nodeA + 1;
    bool hasB = nodeB < N_NODES;
    int p0A = rowoff[nodeA], p1A = rowoff[nodeA + 1];
    int p0B = hasB ? rowoff[nodeB] : 0;
    int p1B = hasB ? rowoff[nodeB + 1] : 0;
    bool act = (c < 12);
    float A0 = 0.f, A1 = 0.f, A2 = 0.f, A3 = 0.f, A4 = 0.f, A5 = 0.f, A6 = 0.f, A7 = 0.f;
    float B0 = 0.f, B1 = 0.f, B2 = 0.f, B3 = 0.f, B4 = 0.f, B5 = 0.f, B6 = 0.f, B7 = 0.f;
    int iters = (max(p1A - p0A, p1B - p0B) + 15) >> 4;
    for (int it = 0; it < iters; ++it) {
        int pbA = p0A + it * 16, pbB = p0B + it * 16;
        int nbA = min(16, p1A - pbA);          // may be <= 0
        int nbB = min(16, p1B - pbB);
        int svA = (c < nbA) ? esrc[pbA + c] : 0;
        int svB = (c < nbB) ? esrc[pbB + c] : 0;
        int nb = max(nbA, nbB);
#pragma unroll 4
        for (int j = 0; j < nb; j++) {
            int sA = __shfl(svA, j, 16);
            int sB = __shfl(svB, j, 16);
            if (act && j < nbA) {
                uint4 v = hb4[(size_t)sA * 12 + c];
                A0 += bflo(v.x); A1 += bfhi(v.x); A2 += bflo(v.y); A3 += bfhi(v.y);
                A4 += bflo(v.z); A5 += bfhi(v.z); A6 += bflo(v.w); A7 += bfhi(v.w);
            }
            if (act && j < nbB) {
                uint4 v = hb4[(size_t)sB * 12 + c];
                B0 += bflo(v.x); B1 += bfhi(v.x); B2 += bflo(v.y); B3 += bfhi(v.y);
                B4 += bflo(v.z); B5 += bfhi(v.z); B6 += bflo(v.w); B7 += bfhi(v.w);
            }
        }
    }
    if (act) {
        float4 b0 = reinterpret_cast<const float4*>(b1)[c * 2];
        float4 b4 = reinterpret_cast<const float4*>(b1)[c * 2 + 1];
        {
            float dv = dis[nodeA];
            uint4 hv = hb4[(size_t)nodeA * 12 + c];
            uint4 o;
            o.x = (unsigned)f2bf(fmaxf((A0 + bflo(hv.x)) * dv + b0.x, 0.f)) |
                  ((unsigned)f2bf(fmaxf((A1 + bfhi(hv.x)) * dv + b0.y, 0.f)) << 16);
            o.y = (unsigned)f2bf(fmaxf((A2 + bflo(hv.y)) * dv + b0.z, 0.f)) |
                  ((unsigned)f2bf(fmaxf((A3 + bfhi(hv.y)) * dv + b0.w, 0.f)) << 16);
            o.z = (unsigned)f2bf(fmaxf((A4 + bflo(hv.z)) * dv + b4.x, 0.f)) |
                  ((unsigned)f2bf(fmaxf((A5 + bfhi(hv.z)) * dv + b4.y, 0.f)) << 16);
            o.w = (unsigned)f2bf(fmaxf((A6 + bflo(hv.w)) * dv + b4.z, 0.f)) |
                  ((unsigned)f2bf(fmaxf((A7 + bfhi(hv.w)) * dv + b4.w, 0.f)) << 16);
            hid4[(size_t)nodeA * 12 + c] = o;
        }
        if (hasB) {
            float dv = dis[nodeB];
            uint4 hv = hb4[(size_t)nodeB * 12 + c];
            uint4 o;
            o.x = (unsigned)f2bf(fmaxf((B0 + bflo(hv.x)) * dv + b0.x, 0.f)) |
                  ((unsigned)f2bf(fmaxf((B1 + bfhi(hv.x)) * dv + b0.y, 0.f)) << 16);
            o.y = (unsigned)f2bf(fmaxf((B2 + bflo(hv.y)) * dv + b0.z, 0.f)) |
                  ((unsigned)f2bf(fmaxf((B3 + bfhi(hv.y)) * dv + b0.w, 0.f)) << 16);
            o.z = (unsigned)f2bf(fmaxf((B4 + bflo(hv.z)) * dv + b4.x, 0.f)) |
                  ((unsigned)f2bf(fmaxf((B5 + bfhi(hv.z)) * dv + b4.y, 0.f)) << 16);
            o.w = (unsigned)f2bf(fmaxf((B6 + bflo(hv.w)) * dv + b4.z, 0.f)) |
                  ((unsigned)f2bf(fmaxf((B7 + bfhi(hv.w)) * dv + b4.w, 0.f)) << 16);
            hid4[(size_t)nodeB * 12 + c] = o;
        }
    }
}

// h23' = (hid @ W2) * dis[row], bf16 MFMA with LDS staging (r17 verified form).
#define GBM2 64
__global__ __launch_bounds__(256) void k_gemm2(const unsigned short* __restrict__ hid,
                                               const unsigned short* __restrict__ W2T,
                                               const float* __restrict__ dis,
                                               unsigned short* __restrict__ h23, int M) {
    __shared__ __align__(16) char lA[64 * 256];    // 16 KB (12/16 slots used)
    __shared__ __align__(16) char lB[64 * 256];    // 16 KB
    int tid = threadIdx.x;
    int lane = tid & 63, w = tid >> 6;
    int l15 = lane & 15, hi = lane >> 4;
    int m0 = blockIdx.x * GBM2;

#pragma unroll
    for (int i = 0; i < 3; ++i) {
        int s = i * 256 + tid;
        int r = s / 12, sl = s - r * 12;
        uint4 v = *reinterpret_cast<const uint4*>(
            hid + (size_t)min(m0 + r, M - 1) * NH + sl * 8);
        *reinterpret_cast<uint4*>(lA + r * 256 + ((sl ^ (r & 7)) << 4)) = v;
    }
#pragma unroll
    for (int i = 0; i < 3; ++i) {
        int s = i * 256 + tid;
        int n = s / 12, sl = s - n * 12;
        uint4 v = *reinterpret_cast<const uint4*>(W2T + (size_t)n * NH + sl * 8);
        *reinterpret_cast<uint4*>(lB + n * 256 + ((sl ^ (n & 7)) << 4)) = v;
    }
    __syncthreads();

    f32x4 acc[4];
#pragma unroll
    for (int nt = 0; nt < 4; ++nt)
#pragma unroll
        for (int i = 0; i < 4; ++i) acc[nt][i] = 0.f;

    int key = l15 & 7;
    const char* aptr = lA + (w * 16 + l15) * 256;
#pragma unroll
    for (int kc = 0; kc < 3; ++kc) {
        int off = (((kc * 4 + hi) ^ key) << 4);
        short8v a = *reinterpret_cast<const short8v*>(aptr + off);
#pragma unroll
        for (int nt = 0; nt < 4; ++nt) {
            short8v bv = *reinterpret_cast<const short8v*>(lB + (nt * 16 + l15) * 256 + off);
            acc[nt] = __builtin_amdgcn_mfma_f32_16x16x32_bf16(a, bv, acc[nt], 0, 0, 0);
        }
    }

    int rbase = m0 + w * 16 + hi * 4;
#pragma unroll
    for (int r = 0; r < 4; ++r) {
        int orow = rbase + r;
        if (orow < M) {
            float dv = dis[orow];
            unsigned short* op = h23 + (size_t)orow * NH2 + l15;
#pragma unroll
            for (int nt = 0; nt < 4; ++nt) op[nt * 16] = f2bf(acc[nt][r] * dv);
        }
    }
}

// gather layer 2: out = (sum h23'[s] + h23'[i]) * dis + bias, split mu/logstd.
// 8-lane groups x TWO nodes each -> 16 independent row-streams per wave.
__global__ __launch_bounds__(256) void k_gather2(const uint4* __restrict__ hb4,
                                                 const int* __restrict__ rowoff,
                                                 const int* __restrict__ esrc,
                                                 const float* __restrict__ dis,
                                                 const float* __restrict__ bmu,
                                                 const float* __restrict__ bls,
                                                 float4* __restrict__ out4) {
    int tid = threadIdx.x;
    int g = tid >> 3, c = tid & 7;
    int nodeA = blockIdx.x * 64 + g * 2;
    if (nodeA >= N_NODES) return;
    int nodeB = nodeA + 1;
    bool hasB = nodeB < N_NODES;
    int p0A = rowoff[nodeA], p1A = rowoff[nodeA + 1];
    int p0B = hasB ? rowoff[nodeB] : 0;
    int p1B = hasB ? rowoff[nodeB + 1] : 0;
    float A0 = 0.f, A1 = 0.f, A2 = 0.f, A3 = 0.f, A4 = 0.f, A5 = 0.f, A6 = 0.f, A7 = 0.f;
    float B0 = 0.f, B1 = 0.f, B2 = 0.f, B3 = 0.f, B4 = 0.f, B5 = 0.f, B6 = 0.f, B7 = 0.f;
    int iters = (max(p1A - p0A, p1B - p0B) + 7) >> 3;
    for (int it = 0; it < iters; ++it) {
        int pbA = p0A + it * 8, pbB = p0B + it * 8;
        int nbA = min(8, p1A - pbA);
        int nbB = min(8, p1B - pbB);
        int svA = (c < nbA) ? esrc[pbA + c] : 0;
        int svB = (c < nbB) ? esrc[pbB + c] : 0;
        int nb = max(nbA, nbB);
#pragma unroll 4
        for (int j = 0; j < nb; j++) {
            int sA = __shfl(svA, j, 8);
            int sB = __shfl(svB, j, 8);
            if (j < nbA) {
                uint4 v = hb4[(size_t)sA * 8 + c];
                A0 += bflo(v.x); A1 += bfhi(v.x); A2 += bflo(v.y); A3 += bfhi(v.y);
                A4 += bflo(v.z); A5 += bfhi(v.z); A6 += bflo(v.w); A7 += bfhi(v.w);
            }
            if (j < nbB) {
                uint4 v = hb4[(size_t)sB * 8 + c];
                B0 += bflo(v.x); B1 += bfhi(v.x); B2 += bflo(v.y); B3 += bfhi(v.y);
                B4 += bflo(v.z); B5 += bfhi(v.z); B6 += bflo(v.w); B7 += bfhi(v.w);
            }
        }
    }
    const float4* bp = (c < 4) ? reinterpret_cast<const float4*>(bmu) + c * 2
                               : reinterpret_cast<const float4*>(bls) + (c - 4) * 2;
    float4 b0 = bp[0], b4 = bp[1];
    {
        float dv = dis[nodeA];
        uint4 hv = hb4[(size_t)nodeA * 8 + c];
        float4 o0, o1;
        o0.x = (A0 + bflo(hv.x)) * dv + b0.x;
        o0.y = (A1 + bfhi(hv.x)) * dv + b0.y;
        o0.z = (A2 + bflo(hv.y)) * dv + b0.z;
        o0.w = (A3 + bfhi(hv.y)) * dv + b0.w;
        o1.x = (A4 + bflo(hv.z)) * dv + b4.x;
        o1.y = (A5 + bfhi(hv.z)) * dv + b4.y;
        o1.z = (A6 + bflo(hv.w)) * dv + b4.z;
        o1.w = (A7 + bfhi(hv.w)) * dv + b4.w;
        size_t base = (c < 4) ? (size_t)nodeA * 8 + c * 2
                              : (size_t)N_NODES * 8 + (size_t)nodeA * 8 + (c - 4) * 2;
        out4[base] = o0;
        out4[base + 1] = o1;
    }
    if (hasB) {
        float dv = dis[nodeB];
        uint4 hv = hb4[(size_t)nodeB * 8 + c];
        float4 o0, o1;
        o0.x = (B0 + bflo(hv.x)) * dv + b0.x;
        o0.y = (B1 + bfhi(hv.x)) * dv + b0.y;
        o0.z = (B2 + bflo(hv.y)) * dv + b0.z;
        o0.w = (B3 + bfhi(hv.y)) * dv + b0.w;
        o1.x = (B4 + bflo(hv.z)) * dv + b4.x;
        o1.y = (B5 + bfhi(hv.z)) * dv + b4.y;
        o1.z = (B6 + bflo(hv.w)) * dv + b4.z;
        o1.w = (B7 + bfhi(hv.w)) * dv + b4.w;
        size_t base = (c < 4) ? (size_t)nodeB * 8 + c * 2
                              : (size_t)N_NODES * 8 + (size_t)nodeB * 8 + (c - 4) * 2;
        out4[base] = o0;
        out4[base + 1] = o1;
    }
}

extern "C" void kernel_launch(void* const* d_in, const int* in_sizes, int n_in,
                              void* d_out, int out_size, void* d_ws, size_t ws_size,
                              hipStream_t stream) {
    const float* x   = (const float*)d_in[0];
    const float* W1  = (const float*)d_in[1];
    const float* b1  = (const float*)d_in[2];
    const float* Wmu = (const float*)d_in[3];
    const float* bmu = (const float*)d_in[4];
    const float* Wls = (const float*)d_in[5];
    const float* bls = (const float*)d_in[6];
    const int*   ei  = (const int*)d_in[7];
    int E = in_sizes[7] / 2;
    const int* src  = ei;
    const int* dstp = ei + E;

    char* w = (char*)d_ws;
    int* rowoff  = (int*)w;            w += ((size_t)N_NODES + 4) * 4;
    float* dis   = (float*)w;          w += (size_t)N_NODES * 4;
    int* gcur    = (int*)w;            w += ((size_t)NB2 + 4) * 4;
    int* esrc    = (int*)w;            w += (size_t)E * 4;
    unsigned* cpair = (unsigned*)w;    w += (size_t)NB2 * BCAP * 4;
    unsigned short* WbT  = (unsigned short*)w;  w += (size_t)NH * NIN * 2;
    unsigned short* W2T  = (unsigned short*)w;  w += (size_t)NH2 * NH * 2;
    unsigned short* hbuf = (unsigned short*)w;  w += (size_t)N_NODES * NH * 2;
    unsigned short* hid  = (unsigned short*)w;  w += (size_t)N_NODES * NH * 2;
    unsigned short* h23  = (unsigned short*)w;  w += (size_t)N_NODES * NH2 * 2;

    int prep_n = NH * NIN + NH2 * NH;
    k_prep<<<(prep_n + 255) / 256, 256, 0, stream>>>(W1, Wmu, Wls, WbT, W2T, gcur);

    k_coarse<<<NBLK, 256, 0, stream>>>(src, dstp, gcur, cpair, E);
    k_fine<<<NB2, 256, 0, stream>>>(cpair, gcur, rowoff, dis, esrc);

    k_gemm1<<<(N_NODES + GBM - 1) / GBM, 256, 0, stream>>>(x, WbT, dis, hbuf, N_NODES);

    k_gather1<<<(N_NODES + 31) / 32, 256, 0, stream>>>(
        (const uint4*)hbuf, rowoff, esrc, dis, b1, (uint4*)hid);

    k_gemm2<<<(N_NODES + GBM2 - 1) / GBM2, 256, 0, stream>>>(hid, W2T, dis, h23, N_NODES);

    k_gather2<<<(N_NODES + 63) / 64, 256, 0, stream>>>(
        (const uint4*)h23, rowoff, esrc, dis, bmu, bls, (float4*)d_out);
}

// Round 22
// 120.892 us; speedup vs baseline: 1.0434x; 1.0434x over previous
//
#include <hip/hip_runtime.h>
#include <hip/hip_bf16.h>

#define N_NODES 50000
#define NIN 512
#define NH 96
#define NL 32
#define NH2 64

#define NB2 196          // coarse buckets of 256 nodes
#define NBLK 128         // binning blocks
#define BCAP 5120        // fixed region capacity per bucket (E[cnt]=4096, +16 sigma)
#define ECH 6250         // edges per coarse block (800000/128)

typedef __attribute__((ext_vector_type(8))) short short8v;   // 8 bf16 (4 VGPR)
typedef __attribute__((ext_vector_type(4))) float f32x4;

__device__ __forceinline__ unsigned short f2bf(float f) {    // RNE via native cvt
    __hip_bfloat16 h = __float2bfloat16(f);
    unsigned short u;
    __builtin_memcpy(&u, &h, 2);
    return u;
}
__device__ __forceinline__ float bflo(unsigned u) { return __uint_as_float(u << 16); }
__device__ __forceinline__ float bfhi(unsigned u) { return __uint_as_float(u & 0xFFFF0000u); }

// fused: WbT = W1^T bf16; W2T = [Wmu|Wls]^T bf16; gcur = 0
__global__ __launch_bounds__(256) void k_prep(const float* __restrict__ W1,
                                              const float* __restrict__ Wmu,
                                              const float* __restrict__ Wls,
                                              unsigned short* __restrict__ WbT,
                                              unsigned short* __restrict__ W2T,
                                              int* __restrict__ gcur) {
    int idx = blockIdx.x * 256 + threadIdx.x;
    if (idx < NH * NIN) {
        int n = idx >> 9, k = idx & 511;
        WbT[idx] = f2bf(W1[(size_t)k * NH + n]);
    } else if (idx < NH * NIN + NH2 * NH) {
        int j = idx - NH * NIN;
        int n = j / NH, k = j - n * NH;
        float v = (n < NL) ? Wmu[k * NL + n] : Wls[k * NL + (n - NL)];
        W2T[j] = f2bf(v);
    }
    if (idx < NB2) gcur[idx] = 0;
}

// pass A: privatized block-run binning; packed pairs cached in LDS during the
// histogram pass. Runs contiguous -> each cache line owned by one block/XCD.
__global__ __launch_bounds__(256) void k_coarse(const int* __restrict__ src,
                                                const int* __restrict__ dst,
                                                int* __restrict__ gcur,
                                                unsigned* __restrict__ cpair, int E) {
    __shared__ unsigned epk[ECH];
    __shared__ int hist[NB2];
    __shared__ int lpos[NB2];
    int t = threadIdx.x;
    int ch = (E + NBLK - 1) / NBLK;
    int e0 = blockIdx.x * ch, e1 = min(e0 + ch, E);
    int n = e1 - e0;
    for (int b = t; b < NB2; b += 256) hist[b] = 0;
    __syncthreads();
    for (int li = t; li < n; li += 256) {
        int s = src[e0 + li], d = dst[e0 + li];
        epk[li] = (unsigned)s | ((unsigned)d << 16);
        atomicAdd(&hist[d >> 8], 1);
    }
    __syncthreads();
    for (int b = t; b < NB2; b += 256) {
        int cnt = hist[b];
        int base = (cnt > 0) ? atomicAdd(&gcur[b], cnt) : 0;
        lpos[b] = b * BCAP + base;
    }
    __syncthreads();
    for (int li = t; li < n; li += 256) {
        unsigned u = epk[li];
        int pos = atomicAdd(&lpos[u >> 24], 1);
        cpair[pos] = u;
    }
}

// pass B: one block per bucket. Computes its own global base, derives per-node
// counts + rowoff + dis, places edges into the bucket's private esrc window.
__global__ __launch_bounds__(256) void k_fine(const unsigned* __restrict__ cpair,
                                              const int* __restrict__ gcur,
                                              int* __restrict__ rowoff,
                                              float* __restrict__ dis,
                                              int* __restrict__ esrc) {
    __shared__ int lcnt[256];
    __shared__ int lscan[256];
    int bb = blockIdx.x;
    int n0 = bb << 8;
    int t = threadIdx.x;
    lscan[t] = (t < bb) ? gcur[t] : 0;
    __syncthreads();
    for (int off = 128; off > 0; off >>= 1) {
        if (t < off) lscan[t] += lscan[t + off];
        __syncthreads();
    }
    int base = lscan[0];
    if (bb == NB2 - 1 && t == 0) rowoff[N_NODES] = base + gcur[bb];
    lcnt[t] = 0;
    __syncthreads();
    int p0 = bb * BCAP;
    int p1 = p0 + gcur[bb];
    for (int p = p0 + t; p < p1; p += 256)
        atomicAdd(&lcnt[(cpair[p] >> 16) - n0], 1);
    __syncthreads();
    int cnt = lcnt[t];
    lscan[t] = cnt;
    __syncthreads();
    for (int off = 1; off < 256; off <<= 1) {
        int u = (t >= off) ? lscan[t - off] : 0;
        __syncthreads();
        lscan[t] += u;
        __syncthreads();
    }
    int excl = lscan[t] - cnt;
    int node = n0 + t;
    if (node < N_NODES) {
        rowoff[node] = base + excl;
        dis[node] = rsqrtf((float)cnt + 1.0f);
    }
    lcnt[t] = base + excl;
    __syncthreads();
    for (int p = p0 + t; p < p1; p += 256) {
        unsigned u = cpair[p];
        int d = (int)(u >> 16);
        int pos = atomicAdd(&lcnt[d - n0], 1);
        esrc[pos] = (int)(u & 0xFFFFu);
    }
}

// h' = (x @ W1) * dis[row], bf16 MFMA 16x16x32 (r20 measured-best config).
// BM=64 (4 waves x 16 rows), BK=128 -> 4 K-tiles, 3 blocks/CU (40KB LDS).
// LDS rows 256B = 16 slots; slot ^= (row&7): conflict-free frag reads.
#define GBM 64
__global__ __launch_bounds__(256, 3) void k_gemm1(const float* __restrict__ x,
                                                  const unsigned short* __restrict__ WbT,
                                                  const float* __restrict__ dis,
                                                  unsigned short* __restrict__ hb, int M) {
    __shared__ __align__(16) char lA[64 * 256];    // 16 KB
    __shared__ __align__(16) char lB[96 * 256];    // 24 KB
    int tid = threadIdx.x;
    int lane = tid & 63, w = tid >> 6;
    int l15 = lane & 15, hi = lane >> 4;
    int m0 = blockIdx.x * GBM;

    f32x4 acc[6];
#pragma unroll
    for (int nt = 0; nt < 6; ++nt)
#pragma unroll
        for (int i = 0; i < 4; ++i) acc[nt][i] = 0.f;

    int key = l15 & 7;
    int arow = (w * 16 + l15) * 256;

    for (int kt = 0; kt < 4; ++kt) {
        __syncthreads();
#pragma unroll
        for (int i = 0; i < 4; ++i) {
            int s = i * 256 + tid;
            int r = s >> 4, sl = s & 15;
            const float* p = x + (size_t)min(m0 + r, M - 1) * NIN + kt * 128 + sl * 8;
            float4 a0 = *reinterpret_cast<const float4*>(p);
            float4 a1 = *reinterpret_cast<const float4*>(p + 4);
            uint4 pk;
            pk.x = (unsigned)f2bf(a0.x) | ((unsigned)f2bf(a0.y) << 16);
            pk.y = (unsigned)f2bf(a0.z) | ((unsigned)f2bf(a0.w) << 16);
            pk.z = (unsigned)f2bf(a1.x) | ((unsigned)f2bf(a1.y) << 16);
            pk.w = (unsigned)f2bf(a1.z) | ((unsigned)f2bf(a1.w) << 16);
            *reinterpret_cast<uint4*>(lA + r * 256 + ((sl ^ (r & 7)) << 4)) = pk;
        }
#pragma unroll
        for (int i = 0; i < 6; ++i) {
            int s = i * 256 + tid;
            int n = s >> 4, sl = s & 15;
            uint4 bv = *reinterpret_cast<const uint4*>(WbT + (size_t)n * NIN + kt * 128 + sl * 8);
            *reinterpret_cast<uint4*>(lB + n * 256 + ((sl ^ (n & 7)) << 4)) = bv;
        }
        __syncthreads();

#pragma unroll
        for (int kc = 0; kc < 4; ++kc) {
            int off = (((kc * 4 + hi) ^ key) << 4);
            short8v a = *reinterpret_cast<const short8v*>(lA + arow + off);
#pragma unroll
            for (int nt = 0; nt < 6; ++nt) {
                short8v bv = *reinterpret_cast<const short8v*>(lB + (nt * 16 + l15) * 256 + off);
                acc[nt] = __builtin_amdgcn_mfma_f32_16x16x32_bf16(a, bv, acc[nt], 0, 0, 0);
            }
        }
    }

    int rbase = m0 + w * 16 + hi * 4;
#pragma unroll
    for (int r = 0; r < 4; ++r) {
        int orow = rbase + r;
        if (orow < M) {
            float dv = dis[orow];
            unsigned short* op = hb + (size_t)orow * NH + l15;
#pragma unroll
            for (int nt = 0; nt < 6; ++nt) op[nt * 16] = f2bf(acc[nt][r] * dv);
        }
    }
}

// gather layer 1 (r20 measured-best): hid = relu((sum h'[s] + h'[i])*dis + b1).
// 16-lane groups, 12 active lanes x uint4 (16B) per 192B row -> 4 independent
// node-streams per wave. (r21's 2-node pairing regressed: past MLP saturation.)
__global__ __launch_bounds__(256) void k_gather1(const uint4* __restrict__ hb4,
                                                 const int* __restrict__ rowoff,
                                                 const int* __restrict__ esrc,
                                                 const float* __restrict__ dis,
                                                 const float* __restrict__ b1,
                                                 uint4* __restrict__ hid4) {
    int tid = threadIdx.x;
    int node = blockIdx.x * 16 + (tid >> 4);
    int c = tid & 15;
    if (node >= N_NODES) return;
    int p0 = rowoff[node], p1 = rowoff[node + 1];
    bool act = (c < 12);
    float a0 = 0.f, a1 = 0.f, a2 = 0.f, a3 = 0.f;
    float a4 = 0.f, a5 = 0.f, a6 = 0.f, a7 = 0.f;
    for (int pb = p0; pb < p1; pb += 16) {
        int nb = min(16, p1 - pb);
        int sv = (c < nb) ? esrc[pb + c] : 0;
#pragma unroll 4
        for (int j = 0; j < nb; j++) {
            int s = __shfl(sv, j, 16);
            if (act) {
                uint4 v = hb4[(size_t)s * 12 + c];
                a0 += bflo(v.x); a1 += bfhi(v.x);
                a2 += bflo(v.y); a3 += bfhi(v.y);
                a4 += bflo(v.z); a5 += bfhi(v.z);
                a6 += bflo(v.w); a7 += bfhi(v.w);
            }
        }
    }
    if (act) {
        float dv = dis[node];
        uint4 hv = hb4[(size_t)node * 12 + c];
        float4 b0 = reinterpret_cast<const float4*>(b1)[c * 2];
        float4 b4 = reinterpret_cast<const float4*>(b1)[c * 2 + 1];
        float r0 = fmaxf((a0 + bflo(hv.x)) * dv + b0.x, 0.f);
        float r1 = fmaxf((a1 + bfhi(hv.x)) * dv + b0.y, 0.f);
        float r2 = fmaxf((a2 + bflo(hv.y)) * dv + b0.z, 0.f);
        float r3 = fmaxf((a3 + bfhi(hv.y)) * dv + b0.w, 0.f);
        float r4 = fmaxf((a4 + bflo(hv.z)) * dv + b4.x, 0.f);
        float r5 = fmaxf((a5 + bfhi(hv.z)) * dv + b4.y, 0.f);
        float r6 = fmaxf((a6 + bflo(hv.w)) * dv + b4.z, 0.f);
        float r7 = fmaxf((a7 + bfhi(hv.w)) * dv + b4.w, 0.f);
        uint4 o;
        o.x = (unsigned)f2bf(r0) | ((unsigned)f2bf(r1) << 16);
        o.y = (unsigned)f2bf(r2) | ((unsigned)f2bf(r3) << 16);
        o.z = (unsigned)f2bf(r4) | ((unsigned)f2bf(r5) << 16);
        o.w = (unsigned)f2bf(r6) | ((unsigned)f2bf(r7) << 16);
        hid4[(size_t)node * 12 + c] = o;
    }
}

// h23' = (hid @ W2) * dis[row], bf16 MFMA with LDS staging (r17 verified form).
#define GBM2 64
__global__ __launch_bounds__(256) void k_gemm2(const unsigned short* __restrict__ hid,
                                               const unsigned short* __restrict__ W2T,
                                               const float* __restrict__ dis,
                                               unsigned short* __restrict__ h23, int M) {
    __shared__ __align__(16) char lA[64 * 256];    // 16 KB (12/16 slots used)
    __shared__ __align__(16) char lB[64 * 256];    // 16 KB
    int tid = threadIdx.x;
    int lane = tid & 63, w = tid >> 6;
    int l15 = lane & 15, hi = lane >> 4;
    int m0 = blockIdx.x * GBM2;

#pragma unroll
    for (int i = 0; i < 3; ++i) {
        int s = i * 256 + tid;
        int r = s / 12, sl = s - r * 12;
        uint4 v = *reinterpret_cast<const uint4*>(
            hid + (size_t)min(m0 + r, M - 1) * NH + sl * 8);
        *reinterpret_cast<uint4*>(lA + r * 256 + ((sl ^ (r & 7)) << 4)) = v;
    }
#pragma unroll
    for (int i = 0; i < 3; ++i) {
        int s = i * 256 + tid;
        int n = s / 12, sl = s - n * 12;
        uint4 v = *reinterpret_cast<const uint4*>(W2T + (size_t)n * NH + sl * 8);
        *reinterpret_cast<uint4*>(lB + n * 256 + ((sl ^ (n & 7)) << 4)) = v;
    }
    __syncthreads();

    f32x4 acc[4];
#pragma unroll
    for (int nt = 0; nt < 4; ++nt)
#pragma unroll
        for (int i = 0; i < 4; ++i) acc[nt][i] = 0.f;

    int key = l15 & 7;
    const char* aptr = lA + (w * 16 + l15) * 256;
#pragma unroll
    for (int kc = 0; kc < 3; ++kc) {
        int off = (((kc * 4 + hi) ^ key) << 4);
        short8v a = *reinterpret_cast<const short8v*>(aptr + off);
#pragma unroll
        for (int nt = 0; nt < 4; ++nt) {
            short8v bv = *reinterpret_cast<const short8v*>(lB + (nt * 16 + l15) * 256 + off);
            acc[nt] = __builtin_amdgcn_mfma_f32_16x16x32_bf16(a, bv, acc[nt], 0, 0, 0);
        }
    }

    int rbase = m0 + w * 16 + hi * 4;
#pragma unroll
    for (int r = 0; r < 4; ++r) {
        int orow = rbase + r;
        if (orow < M) {
            float dv = dis[orow];
            unsigned short* op = h23 + (size_t)orow * NH2 + l15;
#pragma unroll
            for (int nt = 0; nt < 4; ++nt) op[nt * 16] = f2bf(acc[nt][r] * dv);
        }
    }
}

// gather layer 2 (r20 measured-best): 8-lane groups x uint4 per 128B row,
// all lanes active -> 8 node-streams per wave; split mu/logstd on write.
__global__ __launch_bounds__(256) void k_gather2(const uint4* __restrict__ hb4,
                                                 const int* __restrict__ rowoff,
                                                 const int* __restrict__ esrc,
                                                 const float* __restrict__ dis,
                                                 const float* __restrict__ bmu,
                                                 const float* __restrict__ bls,
                                                 float4* __restrict__ out4) {
    int tid = threadIdx.x;
    int node = blockIdx.x * 32 + (tid >> 3);
    int c = tid & 7;
    if (node >= N_NODES) return;
    int p0 = rowoff[node], p1 = rowoff[node + 1];
    float a0 = 0.f, a1 = 0.f, a2 = 0.f, a3 = 0.f;
    float a4 = 0.f, a5 = 0.f, a6 = 0.f, a7 = 0.f;
    for (int pb = p0; pb < p1; pb += 8) {
        int nb = min(8, p1 - pb);
        int sv = (c < nb) ? esrc[pb + c] : 0;
#pragma unroll 4
        for (int j = 0; j < nb; j++) {
            int s = __shfl(sv, j, 8);
            uint4 v = hb4[(size_t)s * 8 + c];
            a0 += bflo(v.x); a1 += bfhi(v.x);
            a2 += bflo(v.y); a3 += bfhi(v.y);
            a4 += bflo(v.z); a5 += bfhi(v.z);
            a6 += bflo(v.w); a7 += bfhi(v.w);
        }
    }
    float dv = dis[node];
    uint4 hv = hb4[(size_t)node * 8 + c];
    const float4* bp = (c < 4) ? reinterpret_cast<const float4*>(bmu) + c * 2
                               : reinterpret_cast<const float4*>(bls) + (c - 4) * 2;
    float4 b0 = bp[0], b4 = bp[1];
    float4 o0, o1;
    o0.x = (a0 + bflo(hv.x)) * dv + b0.x;
    o0.y = (a1 + bfhi(hv.x)) * dv + b0.y;
    o0.z = (a2 + bflo(hv.y)) * dv + b0.z;
    o0.w = (a3 + bfhi(hv.y)) * dv + b0.w;
    o1.x = (a4 + bflo(hv.z)) * dv + b4.x;
    o1.y = (a5 + bfhi(hv.z)) * dv + b4.y;
    o1.z = (a6 + bflo(hv.w)) * dv + b4.z;
    o1.w = (a7 + bfhi(hv.w)) * dv + b4.w;
    size_t base = (c < 4) ? (size_t)node * 8 + c * 2
                          : (size_t)N_NODES * 8 + (size_t)node * 8 + (c - 4) * 2;
    out4[base] = o0;
    out4[base + 1] = o1;
}

extern "C" void kernel_launch(void* const* d_in, const int* in_sizes, int n_in,
                              void* d_out, int out_size, void* d_ws, size_t ws_size,
                              hipStream_t stream) {
    const float* x   = (const float*)d_in[0];
    const float* W1  = (const float*)d_in[1];
    const float* b1  = (const float*)d_in[2];
    const float* Wmu = (const float*)d_in[3];
    const float* bmu = (const float*)d_in[4];
    const float* Wls = (const float*)d_in[5];
    const float* bls = (const float*)d_in[6];
    const int*   ei  = (const int*)d_in[7];
    int E = in_sizes[7] / 2;
    const int* src  = ei;
    const int* dstp = ei + E;

    char* w = (char*)d_ws;
    int* rowoff  = (int*)w;            w += ((size_t)N_NODES + 4) * 4;
    float* dis   = (float*)w;          w += (size_t)N_NODES * 4;
    int* gcur    = (int*)w;            w += ((size_t)NB2 + 4) * 4;
    int* esrc    = (int*)w;            w += (size_t)E * 4;
    unsigned* cpair = (unsigned*)w;    w += (size_t)NB2 * BCAP * 4;
    unsigned short* WbT  = (unsigned short*)w;  w += (size_t)NH * NIN * 2;
    unsigned short* W2T  = (unsigned short*)w;  w += (size_t)NH2 * NH * 2;
    unsigned short* hbuf = (unsigned short*)w;  w += (size_t)N_NODES * NH * 2;
    unsigned short* hid  = (unsigned short*)w;  w += (size_t)N_NODES * NH * 2;
    unsigned short* h23  = (unsigned short*)w;  w += (size_t)N_NODES * NH2 * 2;

    int prep_n = NH * NIN + NH2 * NH;
    k_prep<<<(prep_n + 255) / 256, 256, 0, stream>>>(W1, Wmu, Wls, WbT, W2T, gcur);

    k_coarse<<<NBLK, 256, 0, stream>>>(src, dstp, gcur, cpair, E);
    k_fine<<<NB2, 256, 0, stream>>>(cpair, gcur, rowoff, dis, esrc);

    k_gemm1<<<(N_NODES + GBM - 1) / GBM, 256, 0, stream>>>(x, WbT, dis, hbuf, N_NODES);

    k_gather1<<<(N_NODES + 15) / 16, 256, 0, stream>>>(
        (const uint4*)hbuf, rowoff, esrc, dis, b1, (uint4*)hid);

    k_gemm2<<<(N_NODES + GBM2 - 1) / GBM2, 256, 0, stream>>>(hid, W2T, dis, h23, N_NODES);

    k_gather2<<<(N_NODES + 31) / 32, 256, 0, stream>>>(
        (const uint4*)h23, rowoff, esrc, dis, bmu, bls, (float4*)d_out);
}